// Round 1
// baseline (4605.066 us; speedup 1.0000x reference)
//
#include <hip/hip_runtime.h>

#define NN 100000
#define NE 3200000
#define NG 512
#define DIN 128
#define F1 32
#define F2 64
#define FC 96
#define NC 10
#define BNEPS 1e-5f

__device__ __forceinline__ void atomAddF(float* p, float v) {
  unsafeAtomicAdd(p, v);
}

// ---- degree (in-degree at dst) ----
__global__ void k_deg(const int* __restrict__ dst, unsigned* __restrict__ cnt) {
  int e = blockIdx.x * blockDim.x + threadIdx.x;
  if (e < NE) atomicAdd(&cnt[dst[e]], 1u);
}

__global__ void k_dinv(float* dinv) {  // in-place: uint count -> float rsqrt(deg+1)
  int i = blockIdx.x * blockDim.x + threadIdx.x;
  if (i < NN) {
    unsigned c = ((unsigned*)dinv)[i];
    dinv[i] = rsqrtf((float)c + 1.0f);
  }
}

__global__ void k_gcount(const int* __restrict__ batch, unsigned* __restrict__ gcount) {
  int i = blockIdx.x * blockDim.x + threadIdx.x;
  if (i < NN) atomicAdd(&gcount[batch[i]], 1u);
}

// ---- h1 = x @ W1   [NN,128]@[128,32] ----
__global__ __launch_bounds__(256) void k_gemm1(const float* __restrict__ x,
                                               const float* __restrict__ W,
                                               float* __restrict__ h1) {
  __shared__ float Ws[DIN * F1];   // 16 KB
  __shared__ float xs[8][DIN];     // 4 KB
  int t = threadIdx.x;
  for (int i = t; i < DIN * F1; i += 256) Ws[i] = W[i];
  int row0 = blockIdx.x * 8;
  for (int i = t; i < 8 * DIN; i += 256) {
    int r = i / DIN, k = i % DIN;
    int row = row0 + r;
    xs[r][k] = (row < NN) ? x[(size_t)row * DIN + k] : 0.f;
  }
  __syncthreads();
  int r = t >> 5, c = t & 31;
  int row = row0 + r;
  if (row < NN) {
    float acc = 0.f;
#pragma unroll
    for (int k = 0; k < DIN; ++k) acc += xs[r][k] * Ws[k * F1 + c];
    h1[(size_t)row * F1 + c] = acc;
  }
}

// ---- x1 init (self-loop + bias) into hcat[:,0:32] ----
__global__ void k_self1(const float* __restrict__ h1, const float* __restrict__ dinv,
                        const float* __restrict__ b1, float* __restrict__ hcat) {
  int idx = blockIdx.x * 256 + threadIdx.x;  // over NN*32
  if (idx < NN * F1) {
    int i = idx >> 5, f = idx & 31;
    float dv = dinv[i];
    hcat[(size_t)i * FC + f] = h1[idx] * dv * dv + b1[f];
  }
}

// ---- edge aggregation 1: hcat[dst,0:32] += h1[src]*norm ----
__global__ void k_agg1(const int* __restrict__ src, const int* __restrict__ dst,
                       const float* __restrict__ dinv, const float* __restrict__ h1,
                       float* __restrict__ hcat) {
  long long tid = (long long)blockIdx.x * 256 + threadIdx.x;  // NE*8 threads
  if (tid >= (long long)NE * 8) return;
  int e = (int)(tid >> 3), q = (int)(tid & 7);
  int s = src[e], d = dst[e];
  float nrm = dinv[s] * dinv[d];
  const float4 hv = *(const float4*)&h1[(size_t)s * F1 + q * 4];
  float* dp = &hcat[(size_t)d * FC + q * 4];
  atomAddF(dp + 0, hv.x * nrm);
  atomAddF(dp + 1, hv.y * nrm);
  atomAddF(dp + 2, hv.z * nrm);
  atomAddF(dp + 3, hv.w * nrm);
}

// ---- h2 = x1 @ W2   [NN,32]@[32,64], x1 = hcat[:,0:32] ----
__global__ __launch_bounds__(256) void k_gemm2(const float* __restrict__ hcat,
                                               const float* __restrict__ W,
                                               float* __restrict__ h2) {
  __shared__ float Ws[F1 * F2];   // 8 KB
  __shared__ float xs[16][F1];    // 2 KB
  int t = threadIdx.x;
  for (int i = t; i < F1 * F2; i += 256) Ws[i] = W[i];
  int row0 = blockIdx.x * 16;
  for (int i = t; i < 16 * F1; i += 256) {
    int r = i >> 5, k = i & 31;
    int row = row0 + r;
    xs[r][k] = (row < NN) ? hcat[(size_t)row * FC + k] : 0.f;
  }
  __syncthreads();
  int c = t & 63;
#pragma unroll
  for (int ri = 0; ri < 4; ++ri) {
    int r = (t >> 6) + ri * 4;
    int row = row0 + r;
    if (row < NN) {
      float acc = 0.f;
#pragma unroll
      for (int k = 0; k < F1; ++k) acc += xs[r][k] * Ws[k * F2 + c];
      h2[(size_t)row * F2 + c] = acc;
    }
  }
}

// ---- x2 init into hcat[:,32:96] ----
__global__ void k_self2(const float* __restrict__ h2, const float* __restrict__ dinv,
                        const float* __restrict__ b2, float* __restrict__ hcat) {
  int idx = blockIdx.x * 256 + threadIdx.x;  // over NN*64
  if (idx < NN * F2) {
    int i = idx >> 6, f = idx & 63;
    float dv = dinv[i];
    hcat[(size_t)i * FC + F1 + f] = h2[idx] * dv * dv + b2[f];
  }
}

// ---- edge aggregation 2: hcat[dst,32:96] += h2[src]*norm ----
__global__ void k_agg2(const int* __restrict__ src, const int* __restrict__ dst,
                       const float* __restrict__ dinv, const float* __restrict__ h2,
                       float* __restrict__ hcat) {
  long long tid = (long long)blockIdx.x * 256 + threadIdx.x;  // NE*16 threads
  if (tid >= (long long)NE * 16) return;
  int e = (int)(tid >> 4), q = (int)(tid & 15);
  int s = src[e], d = dst[e];
  float nrm = dinv[s] * dinv[d];
  const float4 hv = *(const float4*)&h2[(size_t)s * F2 + q * 4];
  float* dp = &hcat[(size_t)d * FC + F1 + q * 4];
  atomAddF(dp + 0, hv.x * nrm);
  atomAddF(dp + 1, hv.y * nrm);
  atomAddF(dp + 2, hv.z * nrm);
  atomAddF(dp + 3, hv.w * nrm);
}

// ---- fused: y = relu(hcat@W+b); colsum/colsumsq; atomicMax into pooled[batch] ----
__global__ __launch_bounds__(384) void k_lin1(const float* __restrict__ hcat,
                                              const float* __restrict__ W,
                                              const float* __restrict__ b,
                                              const int* __restrict__ batch,
                                              float* __restrict__ pooled,
                                              float* __restrict__ colsum,
                                              float* __restrict__ colsumsq) {
  __shared__ float Ws[FC * FC];   // 36.8 KB
  __shared__ float xs[16][FC];    // 6 KB
  __shared__ int bt[16];
  __shared__ float ps[4][FC], pq[4][FC];
  int t = threadIdx.x;
  for (int i = t; i < FC * FC; i += 384) Ws[i] = W[i];
  int row0 = blockIdx.x * 16;
  for (int i = t; i < 16 * FC; i += 384) {
    int r = i / FC, k = i % FC;
    int row = row0 + r;
    xs[r][k] = (row < NN) ? hcat[(size_t)row * FC + k] : 0.f;
  }
  if (t < 16) bt[t] = (row0 + t < NN) ? batch[row0 + t] : -1;
  __syncthreads();
  int c = t % FC, rq = t / FC;  // rq in 0..3
  float bias = b[c];
  float psum = 0.f, psq = 0.f;
#pragma unroll
  for (int rr = 0; rr < 4; ++rr) {
    int r = rq * 4 + rr;
    int row = row0 + r;
    if (row < NN) {
      float acc = bias;
#pragma unroll
      for (int k = 0; k < FC; ++k) acc += xs[r][k] * Ws[k * FC + c];
      float v = fmaxf(acc, 0.f);
      psum += v;
      psq += v * v;
      atomicMax((int*)&pooled[(size_t)bt[r] * FC + c], __float_as_int(v));
    }
  }
  ps[rq][c] = psum;
  pq[rq][c] = psq;
  __syncthreads();
  if (rq == 0) {
    float s = ps[0][c] + ps[1][c] + ps[2][c] + ps[3][c];
    float q2 = pq[0][c] + pq[1][c] + pq[2][c] + pq[3][c];
    atomAddF(&colsum[c], s);
    atomAddF(&colsumsq[c], q2);
  }
}

// ---- BN-apply on pooled (with empty-segment guard) ----
__global__ void k_poolbn(const float* __restrict__ pooled, const float* __restrict__ colsum,
                         const float* __restrict__ colsumsq, const unsigned* __restrict__ gcount,
                         const float* __restrict__ g1, const float* __restrict__ bt1,
                         float* __restrict__ pbn) {
  int idx = blockIdx.x * 256 + threadIdx.x;  // NG*FC
  if (idx < NG * FC) {
    int g = idx / FC, c = idx % FC;
    float m = colsum[c] * (1.f / NN);
    float var = colsumsq[c] * (1.f / NN) - m * m;
    float rs = rsqrtf(var + BNEPS);
    float v = (gcount[g] > 0) ? (g1[c] * (pooled[idx] - m) * rs + bt1[c]) : 0.f;
    pbn[idx] = v;
  }
}

// ---- small MLP block: out[:,c] = BN(relu(X@W+b))[:,c], one block per column ----
__global__ __launch_bounds__(256) void k_mlp(const float* __restrict__ X, int ncol,
                                             const float* __restrict__ W,
                                             const float* __restrict__ b,
                                             const float* __restrict__ g,
                                             const float* __restrict__ bt,
                                             float* __restrict__ out) {
  int c = blockIdx.x;
  int t = threadIdx.x;
  __shared__ float vals[NG];
  __shared__ float red[256], redq[256];
  __shared__ float wc[FC];
  if (t < FC) wc[t] = W[(size_t)t * ncol + c];
  __syncthreads();
  float psum = 0.f, psq = 0.f;
  for (int r = t; r < NG; r += 256) {
    float acc = b[c];
#pragma unroll
    for (int k = 0; k < FC; ++k) acc += X[(size_t)r * FC + k] * wc[k];
    float v = fmaxf(acc, 0.f);
    vals[r] = v;
    psum += v;
    psq += v * v;
  }
  red[t] = psum;
  redq[t] = psq;
  __syncthreads();
  for (int s = 128; s > 0; s >>= 1) {
    if (t < s) { red[t] += red[t + s]; redq[t] += redq[t + s]; }
    __syncthreads();
  }
  float m = red[0] * (1.f / NG);
  float var = redq[0] * (1.f / NG) - m * m;
  float rs = rsqrtf(var + BNEPS);
  float gg = g[c], bb = bt[c];
  for (int r = t; r < NG; r += 256) {
    out[(size_t)r * ncol + c] = gg * (vals[r] - m) * rs + bb;
  }
}

extern "C" void kernel_launch(void* const* d_in, const int* in_sizes, int n_in,
                              void* d_out, int out_size, void* d_ws, size_t ws_size,
                              hipStream_t stream) {
  const float* x    = (const float*)d_in[0];
  const int* ei     = (const int*)d_in[1];
  const int* src    = ei;
  const int* dst    = ei + NE;
  const int* batch  = (const int*)d_in[2];
  const float* W1   = (const float*)d_in[3];
  const float* b1   = (const float*)d_in[4];
  const float* W2   = (const float*)d_in[5];
  const float* b2   = (const float*)d_in[6];
  const float* l1W  = (const float*)d_in[7];
  const float* l1b  = (const float*)d_in[8];
  const float* l1g  = (const float*)d_in[9];
  const float* l1bt = (const float*)d_in[10];
  const float* m1W  = (const float*)d_in[11];
  const float* m1b  = (const float*)d_in[12];
  const float* m1g  = (const float*)d_in[13];
  const float* m1bt = (const float*)d_in[14];
  const float* m2W  = (const float*)d_in[15];
  const float* m2b  = (const float*)d_in[16];
  const float* m2g  = (const float*)d_in[17];
  const float* m2bt = (const float*)d_in[18];
  float* out = (float*)d_out;

  float* ws = (float*)d_ws;
  // workspace layout (floats)
  const size_t o_dinv   = 0;                    // 100352 (also uint counts)
  const size_t o_pooled = 100352;               // 49152
  const size_t o_csum   = o_pooled + 49152;     // 128
  const size_t o_csq    = o_csum + 128;         // 128
  const size_t o_gcnt   = o_csq + 128;          // 512
  const size_t o_h1     = o_gcnt + 512;         // 3,200,000
  const size_t o_h2     = o_h1 + (size_t)NN * F1;     // 6,400,000
  const size_t o_hcat   = o_h2 + (size_t)NN * F2;     // 9,600,000
  const size_t o_pbn    = o_hcat + (size_t)NN * FC;   // 49152
  const size_t o_h3     = o_pbn + (size_t)NG * FC;    // 49152

  float* dinv   = ws + o_dinv;
  float* pooled = ws + o_pooled;
  float* csum   = ws + o_csum;
  float* csq    = ws + o_csq;
  unsigned* gcnt = (unsigned*)(ws + o_gcnt);
  float* h1   = ws + o_h1;
  float* h2   = ws + o_h2;
  float* hcat = ws + o_hcat;
  float* pbn  = ws + o_pbn;
  float* h3   = ws + o_h3;

  // zero: counts + pooled + colsums + gcount (contiguous prefix region)
  hipMemsetAsync(ws, 0, (o_h1) * sizeof(float), stream);

  k_deg<<<(NE + 255) / 256, 256, 0, stream>>>(dst, (unsigned*)dinv);
  k_dinv<<<(NN + 255) / 256, 256, 0, stream>>>(dinv);
  k_gcount<<<(NN + 255) / 256, 256, 0, stream>>>(batch, gcnt);

  k_gemm1<<<(NN + 7) / 8, 256, 0, stream>>>(x, W1, h1);
  k_self1<<<(NN * F1 + 255) / 256, 256, 0, stream>>>(h1, dinv, b1, hcat);
  k_agg1<<<(int)(((long long)NE * 8 + 255) / 256), 256, 0, stream>>>(src, dst, dinv, h1, hcat);

  k_gemm2<<<(NN + 15) / 16, 256, 0, stream>>>(hcat, W2, h2);
  k_self2<<<(NN * F2 + 255) / 256, 256, 0, stream>>>(h2, dinv, b2, hcat);
  k_agg2<<<(int)(((long long)NE * 16 + 255) / 256), 256, 0, stream>>>(src, dst, dinv, h2, hcat);

  k_lin1<<<(NN + 15) / 16, 384, 0, stream>>>(hcat, l1W, l1b, batch, pooled, csum, csq);
  k_poolbn<<<(NG * FC + 255) / 256, 256, 0, stream>>>(pooled, csum, csq, gcnt, l1g, l1bt, pbn);

  k_mlp<<<FC, 256, 0, stream>>>(pbn, FC, m1W, m1b, m1g, m1bt, h3);
  k_mlp<<<NC, 256, 0, stream>>>(h3, NC, m2W, m2b, m2g, m2bt, out);
}

// Round 2
// 993.377 us; speedup vs baseline: 4.6358x; 4.6358x over previous
//
#include <hip/hip_runtime.h>

#define NN 100000
#define NE 3200000
#define NG 512
#define DIN 128
#define F1 32
#define F2 64
#define FC 96
#define NC 10
#define BNEPS 1e-5f

#define SCAN_CHUNK 1024
#define SCAN_NB ((NN + SCAN_CHUNK - 1) / SCAN_CHUNK)  // 98

__device__ __forceinline__ void atomAddF(float* p, float v) {
  unsafeAtomicAdd(p, v);
}

// ---- degree (in-degree at dst) ----
__global__ void k_deg(const int* __restrict__ dst, unsigned* __restrict__ cnt) {
  int e = blockIdx.x * blockDim.x + threadIdx.x;
  if (e < NE) atomicAdd(&cnt[dst[e]], 1u);
}

__global__ void k_dinv(const unsigned* __restrict__ deg, float* __restrict__ dinv) {
  int i = blockIdx.x * blockDim.x + threadIdx.x;
  if (i < NN) dinv[i] = rsqrtf((float)deg[i] + 1.0f);
}

__global__ void k_gcount(const int* __restrict__ batch, unsigned* __restrict__ gcount) {
  int i = blockIdx.x * blockDim.x + threadIdx.x;
  if (i < NN) atomicAdd(&gcount[batch[i]], 1u);
}

// ---- exclusive scan of deg -> offs (3-phase) ----
__global__ __launch_bounds__(256) void k_scan1(const unsigned* __restrict__ deg,
                                               int* __restrict__ offs,
                                               unsigned* __restrict__ bsum) {
  __shared__ unsigned ts[256];
  int b = blockIdx.x, t = threadIdx.x;
  int base = b * SCAN_CHUNK + t * 4;
  unsigned v[4];
#pragma unroll
  for (int k = 0; k < 4; ++k) {
    int i = base + k;
    v[k] = (i < NN) ? deg[i] : 0u;
  }
  unsigned s = v[0] + v[1] + v[2] + v[3];
  ts[t] = s;
  __syncthreads();
  for (int d = 1; d < 256; d <<= 1) {
    unsigned add = (t >= d) ? ts[t - d] : 0u;
    __syncthreads();
    ts[t] += add;
    __syncthreads();
  }
  unsigned excl = ts[t] - s;
  if (t == 255) bsum[b] = ts[255];
  unsigned run = excl;
#pragma unroll
  for (int k = 0; k < 4; ++k) {
    int i = base + k;
    if (i < NN) offs[i] = (int)run;
    run += v[k];
  }
}

__global__ void k_scan2(unsigned* bsum) {
  if (threadIdx.x == 0 && blockIdx.x == 0) {
    unsigned run = 0;
    for (int i = 0; i < SCAN_NB; ++i) { unsigned v = bsum[i]; bsum[i] = run; run += v; }
  }
}

__global__ void k_scan3(int* __restrict__ offs, int* __restrict__ cursor,
                        const unsigned* __restrict__ bsum) {
  int i = blockIdx.x * 256 + threadIdx.x;
  if (i < NN) {
    int o = offs[i] + (int)bsum[i >> 10];
    offs[i] = o;
    cursor[i] = o;
  }
  if (i == 0) offs[NN] = NE;
}

// ---- CSR scatter: csr[pos] = src, grouped by dst ----
__global__ void k_scatter(const int* __restrict__ src, const int* __restrict__ dst,
                          int* __restrict__ cursor, int* __restrict__ csr) {
  int e = blockIdx.x * 256 + threadIdx.x;
  if (e < NE) {
    int d = dst[e];
    int pos = atomicAdd(&cursor[d], 1);
    csr[pos] = src[e];
  }
}

// ---- h1s = (x @ W1) * dinv[row]   [NN,128]@[128,32] ----
__global__ __launch_bounds__(256) void k_gemm1(const float* __restrict__ x,
                                               const float* __restrict__ W,
                                               const float* __restrict__ dinv,
                                               float* __restrict__ h1s) {
  __shared__ float Ws[DIN * F1];   // 16 KB
  __shared__ float xs[8][DIN];     // 4 KB
  int t = threadIdx.x;
  for (int i = t; i < DIN * F1; i += 256) Ws[i] = W[i];
  int row0 = blockIdx.x * 8;
  for (int i = t; i < 8 * DIN; i += 256) {
    int r = i / DIN, k = i % DIN;
    int row = row0 + r;
    xs[r][k] = (row < NN) ? x[(size_t)row * DIN + k] : 0.f;
  }
  __syncthreads();
  int r = t >> 5, c = t & 31;
  int row = row0 + r;
  if (row < NN) {
    float acc = 0.f;
#pragma unroll
    for (int k = 0; k < DIN; ++k) acc += xs[r][k] * Ws[k * F1 + c];
    h1s[(size_t)row * F1 + c] = acc * dinv[row];
  }
}

// ---- CSR gather-reduce over 32-wide pre-scaled features ----
// out1[node*out1_stride + f] = dinv[node]*(hs[node]+sum_{s in N(node)} hs[s]) (+ bias)
// out2 (optional) = out1_value * dinv[node], stride 32
__global__ __launch_bounds__(256) void k_gather(const float* __restrict__ hs,
                                                const int* __restrict__ offs,
                                                const int* __restrict__ csr,
                                                const float* __restrict__ dinv,
                                                const float* __restrict__ bias,
                                                float* __restrict__ out1, int out1_stride,
                                                float* __restrict__ out2) {
  int node = blockIdx.x * 4 + (threadIdx.x >> 6);
  if (node >= NN) return;
  int lane = threadIdx.x & 63;
  int f = lane & 31, half = lane >> 5;
  int beg = offs[node], end = offs[node + 1];
  float acc = 0.f;
  int j = beg + half;
  for (; j + 2 < end; j += 4) {  // 2 edges in flight per half
    int s0 = csr[j], s1 = csr[j + 2];
    acc += hs[(size_t)s0 * F1 + f] + hs[(size_t)s1 * F1 + f];
  }
  if (j < end) acc += hs[(size_t)csr[j] * F1 + f];
  acc += __shfl_xor(acc, 32);
  if (half == 0) {
    float dv = dinv[node];
    float v = dv * (hs[(size_t)node * F1 + f] + acc);
    if (bias) v += bias[f];
    out1[(size_t)node * out1_stride + f] = v;
    if (out2) out2[(size_t)node * F1 + f] = v * dv;
  }
}

// ---- hcat[:,32:96] = a1 @ W2 + b2   [NN,32]@[32,64] ----
__global__ __launch_bounds__(256) void k_gemm2(const float* __restrict__ a1,
                                               const float* __restrict__ W,
                                               const float* __restrict__ b2,
                                               float* __restrict__ hcat) {
  __shared__ float Ws[F1 * F2];   // 8 KB
  __shared__ float xs[16][F1];    // 2 KB
  int t = threadIdx.x;
  for (int i = t; i < F1 * F2; i += 256) Ws[i] = W[i];
  int row0 = blockIdx.x * 16;
  for (int i = t; i < 16 * F1; i += 256) {
    int r = i >> 5, k = i & 31;
    int row = row0 + r;
    xs[r][k] = (row < NN) ? a1[(size_t)row * F1 + k] : 0.f;
  }
  __syncthreads();
  int c = t & 63;
  float bias = b2[c];
#pragma unroll
  for (int ri = 0; ri < 4; ++ri) {
    int r = (t >> 6) + ri * 4;
    int row = row0 + r;
    if (row < NN) {
      float acc = 0.f;
#pragma unroll
      for (int k = 0; k < F1; ++k) acc += xs[r][k] * Ws[k * F2 + c];
      hcat[(size_t)row * FC + F1 + c] = acc + bias;
    }
  }
}

// ---- fused: y = relu(hcat@W+b); colsum/colsumsq; atomicMax into pooled[batch] ----
__global__ __launch_bounds__(384) void k_lin1(const float* __restrict__ hcat,
                                              const float* __restrict__ W,
                                              const float* __restrict__ b,
                                              const int* __restrict__ batch,
                                              float* __restrict__ pooled,
                                              float* __restrict__ colsum,
                                              float* __restrict__ colsumsq) {
  __shared__ float Ws[FC * FC];   // 36.8 KB
  __shared__ float xs[16][FC];    // 6 KB
  __shared__ int bt[16];
  __shared__ float ps[4][FC], pq[4][FC];
  int t = threadIdx.x;
  for (int i = t; i < FC * FC; i += 384) Ws[i] = W[i];
  int row0 = blockIdx.x * 16;
  for (int i = t; i < 16 * FC; i += 384) {
    int r = i / FC, k = i % FC;
    int row = row0 + r;
    xs[r][k] = (row < NN) ? hcat[(size_t)row * FC + k] : 0.f;
  }
  if (t < 16) bt[t] = (row0 + t < NN) ? batch[row0 + t] : -1;
  __syncthreads();
  int c = t % FC, rq = t / FC;  // rq in 0..3
  float bias = b[c];
  float psum = 0.f, psq = 0.f;
#pragma unroll
  for (int rr = 0; rr < 4; ++rr) {
    int r = rq * 4 + rr;
    int row = row0 + r;
    if (row < NN) {
      float acc = bias;
#pragma unroll
      for (int k = 0; k < FC; ++k) acc += xs[r][k] * Ws[k * FC + c];
      float v = fmaxf(acc, 0.f);
      psum += v;
      psq += v * v;
      atomicMax((int*)&pooled[(size_t)bt[r] * FC + c], __float_as_int(v));
    }
  }
  ps[rq][c] = psum;
  pq[rq][c] = psq;
  __syncthreads();
  if (rq == 0) {
    float s = ps[0][c] + ps[1][c] + ps[2][c] + ps[3][c];
    float q2 = pq[0][c] + pq[1][c] + pq[2][c] + pq[3][c];
    atomAddF(&colsum[c], s);
    atomAddF(&colsumsq[c], q2);
  }
}

// ---- BN-apply on pooled (with empty-segment guard) ----
__global__ void k_poolbn(const float* __restrict__ pooled, const float* __restrict__ colsum,
                         const float* __restrict__ colsumsq, const unsigned* __restrict__ gcount,
                         const float* __restrict__ g1, const float* __restrict__ bt1,
                         float* __restrict__ pbn) {
  int idx = blockIdx.x * 256 + threadIdx.x;  // NG*FC
  if (idx < NG * FC) {
    int g = idx / FC, c = idx % FC;
    float m = colsum[c] * (1.f / NN);
    float var = colsumsq[c] * (1.f / NN) - m * m;
    float rs = rsqrtf(var + BNEPS);
    float v = (gcount[g] > 0) ? (g1[c] * (pooled[idx] - m) * rs + bt1[c]) : 0.f;
    pbn[idx] = v;
  }
}

// ---- small MLP block: out[:,c] = BN(relu(X@W+b))[:,c], one block per column ----
__global__ __launch_bounds__(256) void k_mlp(const float* __restrict__ X, int ncol,
                                             const float* __restrict__ W,
                                             const float* __restrict__ b,
                                             const float* __restrict__ g,
                                             const float* __restrict__ bt,
                                             float* __restrict__ out) {
  int c = blockIdx.x;
  int t = threadIdx.x;
  __shared__ float vals[NG];
  __shared__ float red[256], redq[256];
  __shared__ float wc[FC];
  if (t < FC) wc[t] = W[(size_t)t * ncol + c];
  __syncthreads();
  float psum = 0.f, psq = 0.f;
  for (int r = t; r < NG; r += 256) {
    float acc = b[c];
#pragma unroll
    for (int k = 0; k < FC; ++k) acc += X[(size_t)r * FC + k] * wc[k];
    float v = fmaxf(acc, 0.f);
    vals[r] = v;
    psum += v;
    psq += v * v;
  }
  red[t] = psum;
  redq[t] = psq;
  __syncthreads();
  for (int s = 128; s > 0; s >>= 1) {
    if (t < s) { red[t] += red[t + s]; redq[t] += redq[t + s]; }
    __syncthreads();
  }
  float m = red[0] * (1.f / NG);
  float var = redq[0] * (1.f / NG) - m * m;
  float rs = rsqrtf(var + BNEPS);
  float gg = g[c], bb = bt[c];
  for (int r = t; r < NG; r += 256) {
    out[(size_t)r * ncol + c] = gg * (vals[r] - m) * rs + bb;
  }
}

extern "C" void kernel_launch(void* const* d_in, const int* in_sizes, int n_in,
                              void* d_out, int out_size, void* d_ws, size_t ws_size,
                              hipStream_t stream) {
  const float* x    = (const float*)d_in[0];
  const int* ei     = (const int*)d_in[1];
  const int* src    = ei;
  const int* dst    = ei + NE;
  const int* batch  = (const int*)d_in[2];
  const float* W1   = (const float*)d_in[3];
  const float* b1   = (const float*)d_in[4];
  const float* W2   = (const float*)d_in[5];
  const float* b2   = (const float*)d_in[6];
  const float* l1W  = (const float*)d_in[7];
  const float* l1b  = (const float*)d_in[8];
  const float* l1g  = (const float*)d_in[9];
  const float* l1bt = (const float*)d_in[10];
  const float* m1W  = (const float*)d_in[11];
  const float* m1b  = (const float*)d_in[12];
  const float* m1g  = (const float*)d_in[13];
  const float* m1bt = (const float*)d_in[14];
  const float* m2W  = (const float*)d_in[15];
  const float* m2b  = (const float*)d_in[16];
  const float* m2g  = (const float*)d_in[17];
  const float* m2bt = (const float*)d_in[18];
  float* out = (float*)d_out;

  float* ws = (float*)d_ws;
  // workspace layout (floats)
  const size_t o_deg    = 0;                       // 100352 (uint)
  const size_t o_pooled = 100352;                  // 49152
  const size_t o_csum   = o_pooled + 49152;        // 128
  const size_t o_csq    = o_csum + 128;            // 128
  const size_t o_gcnt   = o_csq + 128;             // 512
  const size_t o_zend   = o_gcnt + 512;            // memset end = 150272
  const size_t o_dinv   = o_zend;                  // 100352
  const size_t o_offs   = o_dinv + 100352;         // 100360 (int, NN+1)
  const size_t o_cursor = o_offs + 100360;         // 100352 (int)
  const size_t o_bsum   = o_cursor + 100352;       // 128 (uint)
  const size_t o_pbn    = o_bsum + 128;            // 49152
  const size_t o_h3     = o_pbn + 49152;           // 49152
  const size_t o_csr    = o_h3 + 49152;            // 3,200,000 (int)
  const size_t o_h1s    = o_csr + (size_t)NE;      // 3,200,000 (also a1 after gather1)
  const size_t o_x1s    = o_h1s + (size_t)NN * F1; // 3,200,000
  const size_t o_hcat   = o_x1s + (size_t)NN * F1; // 9,600,000

  unsigned* deg  = (unsigned*)(ws + o_deg);
  float* pooled  = ws + o_pooled;
  float* csum    = ws + o_csum;
  float* csq     = ws + o_csq;
  unsigned* gcnt = (unsigned*)(ws + o_gcnt);
  float* dinv    = ws + o_dinv;
  int* offs      = (int*)(ws + o_offs);
  int* cursor    = (int*)(ws + o_cursor);
  unsigned* bsum = (unsigned*)(ws + o_bsum);
  float* pbn     = ws + o_pbn;
  float* h3      = ws + o_h3;
  int* csr       = (int*)(ws + o_csr);
  float* h1s     = ws + o_h1s;
  float* a1      = ws + o_h1s;   // alias: h1s dead after gather1
  float* x1s     = ws + o_x1s;
  float* hcat    = ws + o_hcat;

  // zero: deg + pooled + colsums + gcount (contiguous prefix region)
  hipMemsetAsync(ws, 0, o_zend * sizeof(float), stream);

  k_deg<<<(NE + 255) / 256, 256, 0, stream>>>(dst, deg);
  k_dinv<<<(NN + 255) / 256, 256, 0, stream>>>(deg, dinv);
  k_gcount<<<(NN + 255) / 256, 256, 0, stream>>>(batch, gcnt);

  k_scan1<<<SCAN_NB, 256, 0, stream>>>(deg, offs, bsum);
  k_scan2<<<1, 64, 0, stream>>>(bsum);
  k_scan3<<<(NN + 255) / 256, 256, 0, stream>>>(offs, cursor, bsum);
  k_scatter<<<(NE + 255) / 256, 256, 0, stream>>>(src, dst, cursor, csr);

  k_gemm1<<<(NN + 7) / 8, 256, 0, stream>>>(x, W1, dinv, h1s);
  // gather1: x1 -> hcat[:,0:32] (+b1), x1s = x1*dinv
  k_gather<<<(NN + 3) / 4, 256, 0, stream>>>(h1s, offs, csr, dinv, b1, hcat, FC, x1s);
  // gather2: a1 = Shat * x1 (32-wide), no bias
  k_gather<<<(NN + 3) / 4, 256, 0, stream>>>(x1s, offs, csr, dinv, (const float*)nullptr, a1, F1,
                                             (float*)nullptr);
  k_gemm2<<<(NN + 15) / 16, 256, 0, stream>>>(a1, W2, b2, hcat);

  k_lin1<<<(NN + 15) / 16, 384, 0, stream>>>(hcat, l1W, l1b, batch, pooled, csum, csq);
  k_poolbn<<<(NG * FC + 255) / 256, 256, 0, stream>>>(pooled, csum, csq, gcnt, l1g, l1bt, pbn);

  k_mlp<<<FC, 256, 0, stream>>>(pbn, FC, m1W, m1b, m1g, m1bt, h3);
  k_mlp<<<NC, 256, 0, stream>>>(h3, NC, m2W, m2b, m2g, m2bt, out);
}